// Round 10
// baseline (322.365 us; speedup 1.0000x reference)
//
#include <hip/hip_runtime.h>
#include <math.h>

// FNO2d: B=4, C=3, H=W=256, L=4, WIDTH=32, M1=M2=12
// R10: (a) k_dinvmlp MLP weights staged in LDS (sK$ held only 16KB; the 18KB
// k-stream thrashed it every wave -> s_waitcnt stalls, VALUBusy 52%). LDS
// 51KB -> 3 blocks/CU, allocator VGPR budget ~168, phases stay spill-free.
// (b) pair-packed sV layout in the ky-DFT tails: (fw,bw) read as one
// ds_read_b64 (tail LDS instrs 381 -> 254 per pass).
//
// ws layout (floats):
//   wpk [4624]     : packed MLP weights [k][32*w0 | b0 | w1*3], +b1 at end
//   cwp [4608]     : packed bypass weights [l][o][32*cw | cb | pad3]
//   h   [8388608]  : activations (B,32,H,W), in place per layer
//   tmp [786432]   : ky-DFT out (B,32,H,12) complex; ALIASED with g
//   hfp [294912]   : 4 x-partials of (B,32,24,12) complex

#define ANG0 0.024543692606170260f  // 2*pi/256

__device__ __forceinline__ float fgelu(float v) {
    // exact-GELU via A&S 7.1.26 erf approx, |err| <= 1.5e-7, branchless
    float u = v * 0.70710678118f;
    float a = fabsf(u);
    float t = __builtin_amdgcn_rcpf(__builtin_fmaf(0.3275911f, a, 1.0f));
    float p = t * __builtin_fmaf(t, __builtin_fmaf(t, __builtin_fmaf(t,
                  __builtin_fmaf(t, 1.061405429f, -1.453152027f),
                  1.421413741f), -0.284496736f), 0.254829592f);
    float e = __expf(-u * u);
    float er = __builtin_fmaf(-p, e, 1.0f);
    er = copysignf(er, u);
    return 0.5f * v * (1.0f + er);
}

__device__ __forceinline__ void fill_csp(float2* sCSP, int tid, int nthr) {
    for (int p = tid; p < 256; p += nthr)
        sCSP[p] = make_float2(cosf(p * ANG0), sinf(p * ANG0));
}

// ky-forward DFT over one (b,x) column, pair-packed layout:
// sVp[o*258 + 2*min(y,256-y) + (y>128)], so (fw,bw) is one b64 read.
__device__ __forceinline__ void ky_dft_tail(const float* sVp, const float2* sCSP,
                                            float* tmp, int b, int x, int y) {
    for (int idx = y; idx < 384; idx += 256) {
        int o = idx / 12, ky = idx % 12;
        const float* vp = sVp + o * 258;
        float vdc = vp[0], v128 = vp[256];
        float aR0 = vdc + ((ky & 1) ? -v128 : v128);
        float aR1 = 0.f, aI0 = 0.f, aI1 = 0.f;
#pragma unroll 4
        for (int yy = 1; yy <= 126; yy += 2) {
            int p0 = (ky * yy) & 255;
            int p1 = (p0 + ky) & 255;
            float2 c0 = sCSP[p0], c1 = sCSP[p1];
            float2 v0 = *reinterpret_cast<const float2*>(vp + 2 * yy);
            float2 v1 = *reinterpret_cast<const float2*>(vp + 2 * (yy + 1));
            aR0 = __builtin_fmaf(v0.x + v0.y, c0.x, aR0);
            aI0 = __builtin_fmaf(v0.x - v0.y, -c0.y, aI0);
            aR1 = __builtin_fmaf(v1.x + v1.y, c1.x, aR1);
            aI1 = __builtin_fmaf(v1.x - v1.y, -c1.y, aI1);
        }
        {   // yy = 127
            int p = (ky * 127) & 255;
            float2 c = sCSP[p];
            float2 v0 = *reinterpret_cast<const float2*>(vp + 254);
            aR0 = __builtin_fmaf(v0.x + v0.y, c.x, aR0);
            aI0 = __builtin_fmaf(v0.x - v0.y, -c.y, aI0);
        }
        reinterpret_cast<float2*>(tmp + (((size_t)(b * 32 + o)) * 256 + x) * 24)[ky] =
            make_float2(aR0 + aR1, aI0 + aI1);
    }
}

__global__ void k_init(const float* __restrict__ w0, const float* __restrict__ b0,
                       const float* __restrict__ w1, const float* __restrict__ b1,
                       const float* __restrict__ cw, const float* __restrict__ cb,
                       float* __restrict__ wpk, float* __restrict__ cwp) {
    int t = threadIdx.x;
    for (int idx = t; idx < 128 * 36; idx += 256) {
        int k = idx / 36, j = idx - k * 36;
        float v;
        if (j < 32)       v = w0[j * 128 + k];
        else if (j == 32) v = b0[k];
        else              v = w1[k * 3 + (j - 33)];
        wpk[idx] = v;
    }
    if (t < 3) wpk[128 * 36 + t] = b1[t];
    for (int idx = t; idx < 4 * 32 * 36; idx += 256) {
        int lo = idx / 36, j = idx - lo * 36;
        int l = lo >> 5, o = lo & 31;
        float v = 0.f;
        if (j < 32)       v = cw[l * 1024 + j * 32 + o];
        else if (j == 32) v = cb[l * 32 + o];
        cwp[idx] = v;
    }
}

// Lift + ky-forward DFT for layer 0.
__global__ __launch_bounds__(256, 4) void k_liftf(const float* __restrict__ xin,
                                                  const float* __restrict__ pw,
                                                  const float* __restrict__ pb,
                                                  float* __restrict__ h,
                                                  float* __restrict__ tmp) {
    __shared__ float sVp[32 * 258];
    __shared__ float2 sCSP[256];
    int b = blockIdx.x >> 8, x = blockIdx.x & 255, y = threadIdx.x;
    fill_csp(sCSP, y, 256);
    int vslot = 2 * ((y <= 128) ? y : 256 - y) + ((y > 128) ? 1 : 0);
    float f0 = xin[((b * 3 + 0) * 256 + x) * 256 + y];
    float f1 = xin[((b * 3 + 1) * 256 + x) * 256 + y];
    float f2 = xin[((b * 3 + 2) * 256 + x) * 256 + y];
    float gx = x * (1.0f / 255.0f), gy = y * (1.0f / 255.0f);
#pragma unroll
    for (int o = 0; o < 32; ++o) {
        float v = pb[o] + f0 * pw[o] + f1 * pw[32 + o] + f2 * pw[64 + o]
                + gx * pw[96 + o] + gy * pw[128 + o];
        h[((b * 32 + o) * 256 + x) * 256 + y] = v;
        sVp[o * 258 + vslot] = v;
    }
    __syncthreads();
    ky_dft_tail(sVp, sCSP, tmp, b, x, y);
}

// kx-forward DFT (4-way x-split): hfp[part][plane][kxi][ky]
__global__ __launch_bounds__(320) void k_dftx(const float* __restrict__ tmp,
                                              float* __restrict__ hfp) {
    __shared__ float sT[1536];
    __shared__ float2 sCSP[256];
    int plane = blockIdx.x >> 2, part = blockIdx.x & 3;
    int x0 = part * 64;
    int tid = threadIdx.x;
    fill_csp(sCSP, tid, 320);
    for (int idx = tid; idx < 1536; idx += 320)
        sT[idx] = tmp[(size_t)plane * 6144 + x0 * 24 + idx];
    __syncthreads();
    if (tid < 288) {
        int kxi = tid / 12, ky = tid % 12;
        int kxv = kxi < 12 ? kxi : 232 + kxi;
        float aR = 0.f, aI = 0.f;
        for (int xp = 0; xp < 64; ++xp) {
            int p = (kxv * (x0 + xp)) & 255;
            float2 cs2 = sCSP[p];
            float tr = sT[xp * 24 + 2 * ky], ti = sT[xp * 24 + 2 * ky + 1];
            aR += tr * cs2.x + ti * cs2.y;
            aI += ti * cs2.x - tr * cs2.y;
        }
        hfp[(((size_t)part * 128 + plane) * 24 + kxi) * 24 + 2 * ky]     = aR;
        hfp[(((size_t)part * 128 + plane) * 24 + kxi) * 24 + 2 * ky + 1] = aI;
    }
}

// Mode mix + kx-inverse, one block per (b,o).
__global__ __launch_bounds__(320) void k_mixcinv(const float* __restrict__ hfp,
                                                 const float* __restrict__ w1r,
                                                 const float* __restrict__ w1i,
                                                 const float* __restrict__ w2r,
                                                 const float* __restrict__ w2i,
                                                 float* __restrict__ g, int l) {
    __shared__ float sA[576];
    __shared__ float2 sCSP[256];
    int b = blockIdx.x >> 5, o = blockIdx.x & 31;
    int tid = threadIdx.x;
    fill_csp(sCSP, tid, 320);
    if (tid < 288) {
        int kxi = tid / 12, ky = tid % 12;
        const float *wr, *wi;
        int rk;
        if (kxi < 12) { wr = w1r; wi = w1i; rk = kxi; }
        else          { wr = w2r; wi = w2i; rk = kxi - 12; }
        size_t wbase = ((size_t)l * 32 * 32) * 144 + (size_t)o * 144 + rk * 12 + ky;
        size_t hbase = (((size_t)(b * 32)) * 24 + kxi) * 24 + 2 * ky;
        float aR = 0.f, aI = 0.f;
#pragma unroll 4
        for (int i = 0; i < 32; ++i) {
            float2 h0 = *reinterpret_cast<const float2*>(hfp + hbase + i * 576);
            float2 h1 = *reinterpret_cast<const float2*>(hfp + 73728 + hbase + i * 576);
            float2 h2 = *reinterpret_cast<const float2*>(hfp + 147456 + hbase + i * 576);
            float2 h3 = *reinterpret_cast<const float2*>(hfp + 221184 + hbase + i * 576);
            float hr = h0.x + h1.x + h2.x + h3.x;
            float hi = h0.y + h1.y + h2.y + h3.y;
            float wrv = wr[wbase + (size_t)i * 4608];
            float wiv = wi[wbase + (size_t)i * 4608];
            aR += hr * wrv - hi * wiv;
            aI += hr * wiv + hi * wrv;
        }
        sA[kxi * 24 + 2 * ky]     = aR;
        sA[kxi * 24 + 2 * ky + 1] = aI;
    }
    __syncthreads();
    if (tid < 256) {
        int x = tid;
        float out[24];
#pragma unroll
        for (int j = 0; j < 24; ++j) out[j] = 0.f;
        for (int kxi = 0; kxi < 24; ++kxi) {
            int kxv = kxi < 12 ? kxi : 232 + kxi;
            int p = (kxv * x) & 255;
            float2 cs2 = sCSP[p];
#pragma unroll
            for (int ky = 0; ky < 12; ++ky) {
                float ar = sA[kxi * 24 + 2 * ky], ai = sA[kxi * 24 + 2 * ky + 1];
                out[2 * ky]     += ar * cs2.x - ai * cs2.y;
                out[2 * ky + 1] += ar * cs2.y + ai * cs2.x;
            }
        }
        float* gp = g + ((size_t)(b * 32 + o)) * 6144 + x * 24;
#pragma unroll
        for (int j = 0; j < 24; ++j) gp[j] = out[j];
    }
}

// Layers 0..2: bypass+spectral+gelu, in-place h, + next-layer ky-DFT.
// g aliases tmp: all g reads precede the barrier; tail writes after.
__attribute__((amdgpu_waves_per_eu(2, 4)))
__global__ __launch_bounds__(256) void k_dinvf(float* __restrict__ h,
                                               const float* __restrict__ g,
                                               const float* __restrict__ cwp,
                                               float* __restrict__ tmp,
                                               int l) {
    __shared__ float sVp[32 * 258];
    __shared__ float2 sCSP[256];
    int b = blockIdx.x >> 8, x = blockIdx.x & 255;
    int y = threadIdx.x;
    fill_csp(sCSP, y, 256);
    int vslot = 2 * ((y <= 128) ? y : 256 - y) + ((y > 128) ? 1 : 0);
    float hreg[32];
#pragma unroll
    for (int i = 0; i < 32; ++i)
        hreg[i] = h[(((size_t)(b * 32 + i)) * 256 + x) * 256 + y];
    __syncthreads();
    float ck[12], sk[12];
#pragma unroll
    for (int ky = 1; ky < 12; ++ky) {
        int p = (ky * y) & 255;
        float2 cs2 = sCSP[p];
        ck[ky] = 2.0f * cs2.x; sk[ky] = 2.0f * cs2.y;
    }
    const float* gb = g + ((size_t)(b * 32) * 256 + x) * 24;
    const float* wb = cwp + l * 32 * 36;
    for (int o = 0; o < 32; ++o) {
        const float* gp = gb + (size_t)o * 6144;   // uniform address
        const float* wp = wb + o * 36;             // uniform address
        float sc0 = gp[0], sc1 = 0.f, ss0 = 0.f, ss1 = 0.f;
#pragma unroll
        for (int ky = 1; ky < 12; ky += 2) {
            sc0 = __builtin_fmaf(gp[2 * ky], ck[ky], sc0);
            ss0 = __builtin_fmaf(gp[2 * ky + 1], sk[ky], ss0);
        }
#pragma unroll
        for (int ky = 2; ky < 12; ky += 2) {
            sc1 = __builtin_fmaf(gp[2 * ky], ck[ky], sc1);
            ss1 = __builtin_fmaf(gp[2 * ky + 1], sk[ky], ss1);
        }
        float spec = (sc0 + sc1) - (ss0 + ss1);
        float va0 = __builtin_fmaf(spec, 1.0f / 65536.0f, wp[32]);
        float va1 = 0.f, va2 = 0.f, va3 = 0.f;
#pragma unroll
        for (int i = 0; i < 32; i += 4) {
            va0 = __builtin_fmaf(hreg[i],     wp[i],     va0);
            va1 = __builtin_fmaf(hreg[i + 1], wp[i + 1], va1);
            va2 = __builtin_fmaf(hreg[i + 2], wp[i + 2], va2);
            va3 = __builtin_fmaf(hreg[i + 3], wp[i + 3], va3);
        }
        float v = (va0 + va1) + (va2 + va3);
        v = fgelu(v);
        h[(((size_t)(b * 32 + o)) * 256 + x) * 256 + y] = v;
        sVp[o * 258 + vslot] = v;
    }
    __syncthreads();
    ky_dft_tail(sVp, sCSP, tmp, b, x, y);
}

// Layer 3 (no gelu, no DFT) fused with the final MLP; h never written.
// MLP weights staged in LDS (sW) — the 18KB uniform k-stream overflowed the
// ~16KB scalar cache, so every wave paid L2 latency per k-group (R9 stall).
// Phase-split through thread-private LDS column sVv[y*33+o] kept from R9.
__global__ __launch_bounds__(256) void k_dinvmlp(const float* __restrict__ h,
                                                 const float* __restrict__ g,
                                                 const float* __restrict__ cwp,
                                                 const float* __restrict__ wpk,
                                                 float* __restrict__ out) {
    __shared__ float sVv[256 * 33];
    __shared__ float sW[4624];
    int b = blockIdx.x >> 8, x = blockIdx.x & 255;
    int y = threadIdx.x;
    float hreg[32];
#pragma unroll
    for (int i = 0; i < 32; ++i)
        hreg[i] = h[(((size_t)(b * 32 + i)) * 256 + x) * 256 + y];
    for (int idx = y; idx < 4611; idx += 256) sW[idx] = wpk[idx];
    __syncthreads();
    float ck[12], sk[12];
#pragma unroll
    for (int ky = 1; ky < 12; ++ky) {
        float ang = ((ky * y) & 255) * ANG0;
        ck[ky] = 2.0f * cosf(ang); sk[ky] = 2.0f * sinf(ang);
    }
    const float* gb = g + ((size_t)(b * 32) * 256 + x) * 24;
    const float* wb = cwp + 3 * 32 * 36;
    float* vcol = sVv + y * 33;
    for (int o = 0; o < 32; ++o) {
        const float* gp = gb + (size_t)o * 6144;   // uniform address
        const float* wp = wb + o * 36;             // uniform address
        float sc0 = gp[0], sc1 = 0.f, ss0 = 0.f, ss1 = 0.f;
#pragma unroll
        for (int ky = 1; ky < 12; ky += 2) {
            sc0 = __builtin_fmaf(gp[2 * ky], ck[ky], sc0);
            ss0 = __builtin_fmaf(gp[2 * ky + 1], sk[ky], ss0);
        }
#pragma unroll
        for (int ky = 2; ky < 12; ky += 2) {
            sc1 = __builtin_fmaf(gp[2 * ky], ck[ky], sc1);
            ss1 = __builtin_fmaf(gp[2 * ky + 1], sk[ky], ss1);
        }
        float spec = (sc0 + sc1) - (ss0 + ss1);
        float va0 = __builtin_fmaf(spec, 1.0f / 65536.0f, wp[32]);
        float va1 = 0.f, va2 = 0.f, va3 = 0.f;
#pragma unroll
        for (int i = 0; i < 32; i += 4) {
            va0 = __builtin_fmaf(hreg[i],     wp[i],     va0);
            va1 = __builtin_fmaf(hreg[i + 1], wp[i + 1], va1);
            va2 = __builtin_fmaf(hreg[i + 2], wp[i + 2], va2);
            va3 = __builtin_fmaf(hreg[i + 3], wp[i + 3], va3);
        }
        vcol[o] = (va0 + va1) + (va2 + va3);   // hreg dead after o==31
    }
    // Phase B: reload v column (thread-private, same-thread LDS ordering).
    float vreg[32];
#pragma unroll
    for (int i = 0; i < 32; ++i) vreg[i] = vcol[i];
    float a0 = sW[4608], a1 = sW[4609], a2 = sW[4610];
#pragma unroll 2
    for (int k = 0; k < 128; ++k) {
        const float* wp = sW + k * 36;             // uniform LDS -> b128 bcast
        float t0 = wp[32], t1 = 0.f, t2 = 0.f, t3 = 0.f;
#pragma unroll
        for (int i = 0; i < 32; i += 4) {
            float4 w4 = *reinterpret_cast<const float4*>(wp + i);
            t0 = __builtin_fmaf(vreg[i],     w4.x, t0);
            t1 = __builtin_fmaf(vreg[i + 1], w4.y, t1);
            t2 = __builtin_fmaf(vreg[i + 2], w4.z, t2);
            t3 = __builtin_fmaf(vreg[i + 3], w4.w, t3);
        }
        float t = fgelu((t0 + t1) + (t2 + t3));
        a0 = __builtin_fmaf(t, wp[33], a0);
        a1 = __builtin_fmaf(t, wp[34], a1);
        a2 = __builtin_fmaf(t, wp[35], a2);
    }
    out[(((size_t)b * 3 + 0) * 256 + x) * 256 + y] = a0;
    out[(((size_t)b * 3 + 1) * 256 + x) * 256 + y] = a1;
    out[(((size_t)b * 3 + 2) * 256 + x) * 256 + y] = a2;
}

extern "C" void kernel_launch(void* const* d_in, const int* in_sizes, int n_in,
                              void* d_out, int out_size, void* d_ws, size_t ws_size,
                              hipStream_t stream) {
    const float* xin  = (const float*)d_in[0];
    const float* pw   = (const float*)d_in[1];
    const float* pb   = (const float*)d_in[2];
    const float* sw1r = (const float*)d_in[3];
    const float* sw1i = (const float*)d_in[4];
    const float* sw2r = (const float*)d_in[5];
    const float* sw2i = (const float*)d_in[6];
    const float* cw   = (const float*)d_in[7];
    const float* cb   = (const float*)d_in[8];
    const float* w0   = (const float*)d_in[9];
    const float* b0   = (const float*)d_in[10];
    const float* w1   = (const float*)d_in[11];
    const float* b1   = (const float*)d_in[12];
    float* out = (float*)d_out;

    float* ws  = (float*)d_ws;
    float* wpk = ws;                  // 4624
    float* cwp = wpk + 4624;          // 4608
    float* h   = cwp + 4608;          // 8388608
    float* tmp = h + 8388608;         // 786432 (aliased with g)
    float* hfp = tmp + 786432;        // 294912
    float* g   = tmp;                 // alias

    k_init<<<1, 256, 0, stream>>>(w0, b0, w1, b1, cw, cb, wpk, cwp);
    k_liftf<<<1024, 256, 0, stream>>>(xin, pw, pb, h, tmp);
    for (int l = 0; l < 4; ++l) {
        k_dftx<<<512, 320, 0, stream>>>(tmp, hfp);
        k_mixcinv<<<128, 320, 0, stream>>>(hfp, sw1r, sw1i, sw2r, sw2i, g, l);
        if (l < 3)
            k_dinvf<<<1024, 256, 0, stream>>>(h, g, cwp, tmp, l);
        else
            k_dinvmlp<<<1024, 256, 0, stream>>>(h, g, cwp, wpk, out);
    }
}

// Round 11
// 310.965 us; speedup vs baseline: 1.0367x; 1.0367x over previous
//
#include <hip/hip_runtime.h>
#include <math.h>

// FNO2d: B=4, C=3, H=W=256, L=4, WIDTH=32, M1=M2=12
// R11: (a) REVERT R10's LDS weight staging in k_dinvmlp (regression: weight
// reads moved from free SGPR-folded operands onto the LDS pipe + occupancy
// dropped to 3 blocks/CU). Scalar weights restored (R9 config, 84us).
// (b) NEW: stage each block's g slice (32x24 = 3KB) in LDS via coalesced
// vector loads — kills the per-o serial s_load/lgkmcnt chain (32 iters x
// ~200cyc L2 latency, SGPR-limited prefetch) in BOTH dinv kernels. g is 3MB
// and block-specific, so it thrashed sK$ by construction; the 4.6KB bypass
// weights stay scalar (sK$-hot across blocks).
//
// ws layout (floats):
//   wpk [4624]     : packed MLP weights [k][32*w0 | b0 | w1*3], +b1 at end
//   cwp [4608]     : packed bypass weights [l][o][32*cw | cb | pad3]
//   h   [8388608]  : activations (B,32,H,W), in place per layer
//   tmp [786432]   : ky-DFT out (B,32,H,12) complex; ALIASED with g
//   hfp [294912]   : 4 x-partials of (B,32,24,12) complex

#define ANG0 0.024543692606170260f  // 2*pi/256

__device__ __forceinline__ float fgelu(float v) {
    // exact-GELU via A&S 7.1.26 erf approx, |err| <= 1.5e-7, branchless
    float u = v * 0.70710678118f;
    float a = fabsf(u);
    float t = __builtin_amdgcn_rcpf(__builtin_fmaf(0.3275911f, a, 1.0f));
    float p = t * __builtin_fmaf(t, __builtin_fmaf(t, __builtin_fmaf(t,
                  __builtin_fmaf(t, 1.061405429f, -1.453152027f),
                  1.421413741f), -0.284496736f), 0.254829592f);
    float e = __expf(-u * u);
    float er = __builtin_fmaf(-p, e, 1.0f);
    er = copysignf(er, u);
    return 0.5f * v * (1.0f + er);
}

__device__ __forceinline__ void fill_csp(float2* sCSP, int tid, int nthr) {
    for (int p = tid; p < 256; p += nthr)
        sCSP[p] = make_float2(cosf(p * ANG0), sinf(p * ANG0));
}

// ky-forward DFT over one (b,x) column, pair-packed layout:
// sVp[o*258 + 2*min(y,256-y) + (y>128)], so (fw,bw) is one b64 read.
__device__ __forceinline__ void ky_dft_tail(const float* sVp, const float2* sCSP,
                                            float* tmp, int b, int x, int y) {
    for (int idx = y; idx < 384; idx += 256) {
        int o = idx / 12, ky = idx % 12;
        const float* vp = sVp + o * 258;
        float vdc = vp[0], v128 = vp[256];
        float aR0 = vdc + ((ky & 1) ? -v128 : v128);
        float aR1 = 0.f, aI0 = 0.f, aI1 = 0.f;
#pragma unroll 4
        for (int yy = 1; yy <= 126; yy += 2) {
            int p0 = (ky * yy) & 255;
            int p1 = (p0 + ky) & 255;
            float2 c0 = sCSP[p0], c1 = sCSP[p1];
            float2 v0 = *reinterpret_cast<const float2*>(vp + 2 * yy);
            float2 v1 = *reinterpret_cast<const float2*>(vp + 2 * (yy + 1));
            aR0 = __builtin_fmaf(v0.x + v0.y, c0.x, aR0);
            aI0 = __builtin_fmaf(v0.x - v0.y, -c0.y, aI0);
            aR1 = __builtin_fmaf(v1.x + v1.y, c1.x, aR1);
            aI1 = __builtin_fmaf(v1.x - v1.y, -c1.y, aI1);
        }
        {   // yy = 127
            int p = (ky * 127) & 255;
            float2 c = sCSP[p];
            float2 v0 = *reinterpret_cast<const float2*>(vp + 254);
            aR0 = __builtin_fmaf(v0.x + v0.y, c.x, aR0);
            aI0 = __builtin_fmaf(v0.x - v0.y, -c.y, aI0);
        }
        reinterpret_cast<float2*>(tmp + (((size_t)(b * 32 + o)) * 256 + x) * 24)[ky] =
            make_float2(aR0 + aR1, aI0 + aI1);
    }
}

__global__ void k_init(const float* __restrict__ w0, const float* __restrict__ b0,
                       const float* __restrict__ w1, const float* __restrict__ b1,
                       const float* __restrict__ cw, const float* __restrict__ cb,
                       float* __restrict__ wpk, float* __restrict__ cwp) {
    int t = threadIdx.x;
    for (int idx = t; idx < 128 * 36; idx += 256) {
        int k = idx / 36, j = idx - k * 36;
        float v;
        if (j < 32)       v = w0[j * 128 + k];
        else if (j == 32) v = b0[k];
        else              v = w1[k * 3 + (j - 33)];
        wpk[idx] = v;
    }
    if (t < 3) wpk[128 * 36 + t] = b1[t];
    for (int idx = t; idx < 4 * 32 * 36; idx += 256) {
        int lo = idx / 36, j = idx - lo * 36;
        int l = lo >> 5, o = lo & 31;
        float v = 0.f;
        if (j < 32)       v = cw[l * 1024 + j * 32 + o];
        else if (j == 32) v = cb[l * 32 + o];
        cwp[idx] = v;
    }
}

// Lift + ky-forward DFT for layer 0.
__global__ __launch_bounds__(256, 4) void k_liftf(const float* __restrict__ xin,
                                                  const float* __restrict__ pw,
                                                  const float* __restrict__ pb,
                                                  float* __restrict__ h,
                                                  float* __restrict__ tmp) {
    __shared__ float sVp[32 * 258];
    __shared__ float2 sCSP[256];
    int b = blockIdx.x >> 8, x = blockIdx.x & 255, y = threadIdx.x;
    fill_csp(sCSP, y, 256);
    int vslot = 2 * ((y <= 128) ? y : 256 - y) + ((y > 128) ? 1 : 0);
    float f0 = xin[((b * 3 + 0) * 256 + x) * 256 + y];
    float f1 = xin[((b * 3 + 1) * 256 + x) * 256 + y];
    float f2 = xin[((b * 3 + 2) * 256 + x) * 256 + y];
    float gx = x * (1.0f / 255.0f), gy = y * (1.0f / 255.0f);
#pragma unroll
    for (int o = 0; o < 32; ++o) {
        float v = pb[o] + f0 * pw[o] + f1 * pw[32 + o] + f2 * pw[64 + o]
                + gx * pw[96 + o] + gy * pw[128 + o];
        h[((b * 32 + o) * 256 + x) * 256 + y] = v;
        sVp[o * 258 + vslot] = v;
    }
    __syncthreads();
    ky_dft_tail(sVp, sCSP, tmp, b, x, y);
}

// kx-forward DFT (4-way x-split): hfp[part][plane][kxi][ky]
__global__ __launch_bounds__(320) void k_dftx(const float* __restrict__ tmp,
                                              float* __restrict__ hfp) {
    __shared__ float sT[1536];
    __shared__ float2 sCSP[256];
    int plane = blockIdx.x >> 2, part = blockIdx.x & 3;
    int x0 = part * 64;
    int tid = threadIdx.x;
    fill_csp(sCSP, tid, 320);
    for (int idx = tid; idx < 1536; idx += 320)
        sT[idx] = tmp[(size_t)plane * 6144 + x0 * 24 + idx];
    __syncthreads();
    if (tid < 288) {
        int kxi = tid / 12, ky = tid % 12;
        int kxv = kxi < 12 ? kxi : 232 + kxi;
        float aR = 0.f, aI = 0.f;
        for (int xp = 0; xp < 64; ++xp) {
            int p = (kxv * (x0 + xp)) & 255;
            float2 cs2 = sCSP[p];
            float tr = sT[xp * 24 + 2 * ky], ti = sT[xp * 24 + 2 * ky + 1];
            aR += tr * cs2.x + ti * cs2.y;
            aI += ti * cs2.x - tr * cs2.y;
        }
        hfp[(((size_t)part * 128 + plane) * 24 + kxi) * 24 + 2 * ky]     = aR;
        hfp[(((size_t)part * 128 + plane) * 24 + kxi) * 24 + 2 * ky + 1] = aI;
    }
}

// Mode mix + kx-inverse, one block per (b,o).
__global__ __launch_bounds__(320) void k_mixcinv(const float* __restrict__ hfp,
                                                 const float* __restrict__ w1r,
                                                 const float* __restrict__ w1i,
                                                 const float* __restrict__ w2r,
                                                 const float* __restrict__ w2i,
                                                 float* __restrict__ g, int l) {
    __shared__ float sA[576];
    __shared__ float2 sCSP[256];
    int b = blockIdx.x >> 5, o = blockIdx.x & 31;
    int tid = threadIdx.x;
    fill_csp(sCSP, tid, 320);
    if (tid < 288) {
        int kxi = tid / 12, ky = tid % 12;
        const float *wr, *wi;
        int rk;
        if (kxi < 12) { wr = w1r; wi = w1i; rk = kxi; }
        else          { wr = w2r; wi = w2i; rk = kxi - 12; }
        size_t wbase = ((size_t)l * 32 * 32) * 144 + (size_t)o * 144 + rk * 12 + ky;
        size_t hbase = (((size_t)(b * 32)) * 24 + kxi) * 24 + 2 * ky;
        float aR = 0.f, aI = 0.f;
#pragma unroll 4
        for (int i = 0; i < 32; ++i) {
            float2 h0 = *reinterpret_cast<const float2*>(hfp + hbase + i * 576);
            float2 h1 = *reinterpret_cast<const float2*>(hfp + 73728 + hbase + i * 576);
            float2 h2 = *reinterpret_cast<const float2*>(hfp + 147456 + hbase + i * 576);
            float2 h3 = *reinterpret_cast<const float2*>(hfp + 221184 + hbase + i * 576);
            float hr = h0.x + h1.x + h2.x + h3.x;
            float hi = h0.y + h1.y + h2.y + h3.y;
            float wrv = wr[wbase + (size_t)i * 4608];
            float wiv = wi[wbase + (size_t)i * 4608];
            aR += hr * wrv - hi * wiv;
            aI += hr * wiv + hi * wrv;
        }
        sA[kxi * 24 + 2 * ky]     = aR;
        sA[kxi * 24 + 2 * ky + 1] = aI;
    }
    __syncthreads();
    if (tid < 256) {
        int x = tid;
        float out[24];
#pragma unroll
        for (int j = 0; j < 24; ++j) out[j] = 0.f;
        for (int kxi = 0; kxi < 24; ++kxi) {
            int kxv = kxi < 12 ? kxi : 232 + kxi;
            int p = (kxv * x) & 255;
            float2 cs2 = sCSP[p];
#pragma unroll
            for (int ky = 0; ky < 12; ++ky) {
                float ar = sA[kxi * 24 + 2 * ky], ai = sA[kxi * 24 + 2 * ky + 1];
                out[2 * ky]     += ar * cs2.x - ai * cs2.y;
                out[2 * ky + 1] += ar * cs2.y + ai * cs2.x;
            }
        }
        float* gp = g + ((size_t)(b * 32 + o)) * 6144 + x * 24;
#pragma unroll
        for (int j = 0; j < 24; ++j) gp[j] = out[j];
    }
}

// Layers 0..2: bypass+spectral+gelu, in-place h, + next-layer ky-DFT.
// g slice staged in sG (coalesced vector loads) — removes the per-o serial
// scalar-load chain. g aliases tmp: sG reads complete before the barrier
// preceding the tail's tmp writes; blocks touch disjoint x.
__attribute__((amdgpu_waves_per_eu(2, 4)))
__global__ __launch_bounds__(256) void k_dinvf(float* __restrict__ h,
                                               const float* __restrict__ g,
                                               const float* __restrict__ cwp,
                                               float* __restrict__ tmp,
                                               int l) {
    __shared__ float sVp[32 * 258];
    __shared__ float2 sCSP[256];
    __shared__ float sG[768];
    int b = blockIdx.x >> 8, x = blockIdx.x & 255;
    int y = threadIdx.x;
    fill_csp(sCSP, y, 256);
    for (int idx = y; idx < 768; idx += 256) {
        int o = idx / 24, j = idx - o * 24;
        sG[idx] = g[(((size_t)(b * 32 + o)) * 256 + x) * 24 + j];
    }
    int vslot = 2 * ((y <= 128) ? y : 256 - y) + ((y > 128) ? 1 : 0);
    float hreg[32];
#pragma unroll
    for (int i = 0; i < 32; ++i)
        hreg[i] = h[(((size_t)(b * 32 + i)) * 256 + x) * 256 + y];
    __syncthreads();
    float ck[12], sk[12];
#pragma unroll
    for (int ky = 1; ky < 12; ++ky) {
        int p = (ky * y) & 255;
        float2 cs2 = sCSP[p];
        ck[ky] = 2.0f * cs2.x; sk[ky] = 2.0f * cs2.y;
    }
    const float* wb = cwp + l * 32 * 36;
    for (int o = 0; o < 32; ++o) {
        const float* gp = sG + o * 24;             // LDS broadcast reads
        const float* wp = wb + o * 36;             // uniform (scalar) address
        float sc0 = gp[0], sc1 = 0.f, ss0 = 0.f, ss1 = 0.f;
#pragma unroll
        for (int ky = 1; ky < 12; ky += 2) {
            sc0 = __builtin_fmaf(gp[2 * ky], ck[ky], sc0);
            ss0 = __builtin_fmaf(gp[2 * ky + 1], sk[ky], ss0);
        }
#pragma unroll
        for (int ky = 2; ky < 12; ky += 2) {
            sc1 = __builtin_fmaf(gp[2 * ky], ck[ky], sc1);
            ss1 = __builtin_fmaf(gp[2 * ky + 1], sk[ky], ss1);
        }
        float spec = (sc0 + sc1) - (ss0 + ss1);
        float va0 = __builtin_fmaf(spec, 1.0f / 65536.0f, wp[32]);
        float va1 = 0.f, va2 = 0.f, va3 = 0.f;
#pragma unroll
        for (int i = 0; i < 32; i += 4) {
            va0 = __builtin_fmaf(hreg[i],     wp[i],     va0);
            va1 = __builtin_fmaf(hreg[i + 1], wp[i + 1], va1);
            va2 = __builtin_fmaf(hreg[i + 2], wp[i + 2], va2);
            va3 = __builtin_fmaf(hreg[i + 3], wp[i + 3], va3);
        }
        float v = (va0 + va1) + (va2 + va3);
        v = fgelu(v);
        h[(((size_t)(b * 32 + o)) * 256 + x) * 256 + y] = v;
        sVp[o * 258 + vslot] = v;
    }
    __syncthreads();
    ky_dft_tail(sVp, sCSP, tmp, b, x, y);
}

// Layer 3 (no gelu, no DFT) fused with the final MLP; h never written.
// Scalar MLP weights (R9 config — LDS staging regressed). Phase-split via
// thread-private LDS column sVv[y*33+o]; g slice staged in sG.
__global__ __launch_bounds__(256) void k_dinvmlp(const float* __restrict__ h,
                                                 const float* __restrict__ g,
                                                 const float* __restrict__ cwp,
                                                 const float* __restrict__ wpk,
                                                 float* __restrict__ out) {
    __shared__ float sVv[256 * 33];
    __shared__ float2 sCSP[256];
    __shared__ float sG[768];
    int b = blockIdx.x >> 8, x = blockIdx.x & 255;
    int y = threadIdx.x;
    fill_csp(sCSP, y, 256);
    for (int idx = y; idx < 768; idx += 256) {
        int o = idx / 24, j = idx - o * 24;
        sG[idx] = g[(((size_t)(b * 32 + o)) * 256 + x) * 24 + j];
    }
    float hreg[32];
#pragma unroll
    for (int i = 0; i < 32; ++i)
        hreg[i] = h[(((size_t)(b * 32 + i)) * 256 + x) * 256 + y];
    __syncthreads();
    float ck[12], sk[12];
#pragma unroll
    for (int ky = 1; ky < 12; ++ky) {
        int p = (ky * y) & 255;
        float2 cs2 = sCSP[p];
        ck[ky] = 2.0f * cs2.x; sk[ky] = 2.0f * cs2.y;
    }
    const float* wb = cwp + 3 * 32 * 36;
    float* vcol = sVv + y * 33;
    for (int o = 0; o < 32; ++o) {
        const float* gp = sG + o * 24;             // LDS broadcast reads
        const float* wp = wb + o * 36;             // uniform (scalar) address
        float sc0 = gp[0], sc1 = 0.f, ss0 = 0.f, ss1 = 0.f;
#pragma unroll
        for (int ky = 1; ky < 12; ky += 2) {
            sc0 = __builtin_fmaf(gp[2 * ky], ck[ky], sc0);
            ss0 = __builtin_fmaf(gp[2 * ky + 1], sk[ky], ss0);
        }
#pragma unroll
        for (int ky = 2; ky < 12; ky += 2) {
            sc1 = __builtin_fmaf(gp[2 * ky], ck[ky], sc1);
            ss1 = __builtin_fmaf(gp[2 * ky + 1], sk[ky], ss1);
        }
        float spec = (sc0 + sc1) - (ss0 + ss1);
        float va0 = __builtin_fmaf(spec, 1.0f / 65536.0f, wp[32]);
        float va1 = 0.f, va2 = 0.f, va3 = 0.f;
#pragma unroll
        for (int i = 0; i < 32; i += 4) {
            va0 = __builtin_fmaf(hreg[i],     wp[i],     va0);
            va1 = __builtin_fmaf(hreg[i + 1], wp[i + 1], va1);
            va2 = __builtin_fmaf(hreg[i + 2], wp[i + 2], va2);
            va3 = __builtin_fmaf(hreg[i + 3], wp[i + 3], va3);
        }
        vcol[o] = (va0 + va1) + (va2 + va3);   // hreg dead after o==31
    }
    // Phase B: reload v column (thread-private, same-thread LDS ordering).
    float vreg[32];
#pragma unroll
    for (int i = 0; i < 32; ++i) vreg[i] = vcol[i];
    float a0 = wpk[128 * 36 + 0], a1 = wpk[128 * 36 + 1], a2 = wpk[128 * 36 + 2];
#pragma unroll 2
    for (int k = 0; k < 128; ++k) {
        const float* wp = wpk + k * 36;            // uniform (scalar) address
        float t0 = wp[32], t1 = 0.f, t2 = 0.f, t3 = 0.f;
#pragma unroll
        for (int i = 0; i < 32; i += 4) {
            t0 = __builtin_fmaf(vreg[i],     wp[i],     t0);
            t1 = __builtin_fmaf(vreg[i + 1], wp[i + 1], t1);
            t2 = __builtin_fmaf(vreg[i + 2], wp[i + 2], t2);
            t3 = __builtin_fmaf(vreg[i + 3], wp[i + 3], t3);
        }
        float t = fgelu((t0 + t1) + (t2 + t3));
        a0 = __builtin_fmaf(t, wp[33], a0);
        a1 = __builtin_fmaf(t, wp[34], a1);
        a2 = __builtin_fmaf(t, wp[35], a2);
    }
    out[(((size_t)b * 3 + 0) * 256 + x) * 256 + y] = a0;
    out[(((size_t)b * 3 + 1) * 256 + x) * 256 + y] = a1;
    out[(((size_t)b * 3 + 2) * 256 + x) * 256 + y] = a2;
}

extern "C" void kernel_launch(void* const* d_in, const int* in_sizes, int n_in,
                              void* d_out, int out_size, void* d_ws, size_t ws_size,
                              hipStream_t stream) {
    const float* xin  = (const float*)d_in[0];
    const float* pw   = (const float*)d_in[1];
    const float* pb   = (const float*)d_in[2];
    const float* sw1r = (const float*)d_in[3];
    const float* sw1i = (const float*)d_in[4];
    const float* sw2r = (const float*)d_in[5];
    const float* sw2i = (const float*)d_in[6];
    const float* cw   = (const float*)d_in[7];
    const float* cb   = (const float*)d_in[8];
    const float* w0   = (const float*)d_in[9];
    const float* b0   = (const float*)d_in[10];
    const float* w1   = (const float*)d_in[11];
    const float* b1   = (const float*)d_in[12];
    float* out = (float*)d_out;

    float* ws  = (float*)d_ws;
    float* wpk = ws;                  // 4624
    float* cwp = wpk + 4624;          // 4608
    float* h   = cwp + 4608;          // 8388608
    float* tmp = h + 8388608;         // 786432 (aliased with g)
    float* hfp = tmp + 786432;        // 294912
    float* g   = tmp;                 // alias

    k_init<<<1, 256, 0, stream>>>(w0, b0, w1, b1, cw, cb, wpk, cwp);
    k_liftf<<<1024, 256, 0, stream>>>(xin, pw, pb, h, tmp);
    for (int l = 0; l < 4; ++l) {
        k_dftx<<<512, 320, 0, stream>>>(tmp, hfp);
        k_mixcinv<<<128, 320, 0, stream>>>(hfp, sw1r, sw1i, sw2r, sw2i, g, l);
        if (l < 3)
            k_dinvf<<<1024, 256, 0, stream>>>(h, g, cwp, tmp, l);
        else
            k_dinvmlp<<<1024, 256, 0, stream>>>(h, g, cwp, wpk, out);
    }
}

// Round 12
// 290.371 us; speedup vs baseline: 1.1102x; 1.0709x over previous
//
#include <hip/hip_runtime.h>
#include <math.h>

// FNO2d: B=4, C=3, H=W=256, L=4, WIDTH=32, M1=M2=12
// R12: k_dinvmlp phase B (the 256x32 @ 32x128 MLP GEMM + gelu + @W1) moved to
// MFMA (16x16x32 bf16, split-bf16 3-pass hi*hi+hi*lo+lo*hi for fp32-grade
// accuracy). Phase A reverted to the R8 config (84us measured: scalar g,
// scalar weights, sCSP table, phase-split via sVv). W0 fragments precomputed
// in k_init in B-lane layout; A fragments built from sVv; W1 contraction via
// per-lane partials + shfl_xor reduce, re-coalesced through sVv.
//
// ws layout (floats/u32):
//   wpk [4624]     : packed MLP weights [k][32*w0 | b0 | w1*3], +b1 at end
//   cwp [4608]     : packed bypass weights [l][o][32*cw | cb | pad3]
//   wB  [4096 u32] : W0 B-fragments, hi[2048] + lo[2048], MFMA lane layout
//   w1p [384]      : W1 column-major [c][k]
//   h   [8388608]  : activations (B,32,H,W), in place per layer
//   tmp [786432]   : ky-DFT out (B,32,H,12) complex; ALIASED with g
//   hfp [294912]   : 4 x-partials of (B,32,24,12) complex

#define ANG0 0.024543692606170260f  // 2*pi/256

typedef __attribute__((ext_vector_type(8))) short bf16x8_t;
typedef __attribute__((ext_vector_type(4))) float f32x4_t;

__device__ __forceinline__ float fgelu(float v) {
    // exact-GELU via A&S 7.1.26 erf approx, |err| <= 1.5e-7, branchless
    float u = v * 0.70710678118f;
    float a = fabsf(u);
    float t = __builtin_amdgcn_rcpf(__builtin_fmaf(0.3275911f, a, 1.0f));
    float p = t * __builtin_fmaf(t, __builtin_fmaf(t, __builtin_fmaf(t,
                  __builtin_fmaf(t, 1.061405429f, -1.453152027f),
                  1.421413741f), -0.284496736f), 0.254829592f);
    float e = __expf(-u * u);
    float er = __builtin_fmaf(-p, e, 1.0f);
    er = copysignf(er, u);
    return 0.5f * v * (1.0f + er);
}

__device__ __forceinline__ void fill_csp(float2* sCSP, int tid, int nthr) {
    for (int p = tid; p < 256; p += nthr)
        sCSP[p] = make_float2(cosf(p * ANG0), sinf(p * ANG0));
}

// ky-forward DFT over one (b,x) column, pair-packed layout:
// sVp[o*258 + 2*min(y,256-y) + (y>128)], so (fw,bw) is one b64 read.
__device__ __forceinline__ void ky_dft_tail(const float* sVp, const float2* sCSP,
                                            float* tmp, int b, int x, int y) {
    for (int idx = y; idx < 384; idx += 256) {
        int o = idx / 12, ky = idx % 12;
        const float* vp = sVp + o * 258;
        float vdc = vp[0], v128 = vp[256];
        float aR0 = vdc + ((ky & 1) ? -v128 : v128);
        float aR1 = 0.f, aI0 = 0.f, aI1 = 0.f;
#pragma unroll 4
        for (int yy = 1; yy <= 126; yy += 2) {
            int p0 = (ky * yy) & 255;
            int p1 = (p0 + ky) & 255;
            float2 c0 = sCSP[p0], c1 = sCSP[p1];
            float2 v0 = *reinterpret_cast<const float2*>(vp + 2 * yy);
            float2 v1 = *reinterpret_cast<const float2*>(vp + 2 * (yy + 1));
            aR0 = __builtin_fmaf(v0.x + v0.y, c0.x, aR0);
            aI0 = __builtin_fmaf(v0.x - v0.y, -c0.y, aI0);
            aR1 = __builtin_fmaf(v1.x + v1.y, c1.x, aR1);
            aI1 = __builtin_fmaf(v1.x - v1.y, -c1.y, aI1);
        }
        {   // yy = 127
            int p = (ky * 127) & 255;
            float2 c = sCSP[p];
            float2 v0 = *reinterpret_cast<const float2*>(vp + 254);
            aR0 = __builtin_fmaf(v0.x + v0.y, c.x, aR0);
            aI0 = __builtin_fmaf(v0.x - v0.y, -c.y, aI0);
        }
        reinterpret_cast<float2*>(tmp + (((size_t)(b * 32 + o)) * 256 + x) * 24)[ky] =
            make_float2(aR0 + aR1, aI0 + aI1);
    }
}

__global__ void k_init(const float* __restrict__ w0, const float* __restrict__ b0,
                       const float* __restrict__ w1, const float* __restrict__ b1,
                       const float* __restrict__ cw, const float* __restrict__ cb,
                       float* __restrict__ wpk, float* __restrict__ cwp,
                       unsigned* __restrict__ wB, float* __restrict__ w1p) {
    int t = threadIdx.x;
    for (int idx = t; idx < 128 * 36; idx += 256) {
        int k = idx / 36, j = idx - k * 36;
        float v;
        if (j < 32)       v = w0[j * 128 + k];
        else if (j == 32) v = b0[k];
        else              v = w1[k * 3 + (j - 33)];
        wpk[idx] = v;
    }
    if (t < 3) wpk[128 * 36 + t] = b1[t];
    for (int idx = t; idx < 4 * 32 * 36; idx += 256) {
        int lo = idx / 36, j = idx - lo * 36;
        int l = lo >> 5, o = lo & 31;
        float v = 0.f;
        if (j < 32)       v = cw[l * 1024 + j * 32 + o];
        else if (j == 32) v = cb[l * 32 + o];
        cwp[idx] = v;
    }
    // W0 MFMA B-fragments: lane l holds B[k=8*(l>>4)+j][col=n*16+(l&15)],
    // j=0..7 packed as 4 u32 (even k in lo16, odd k in hi16). hi then lo.
    for (int idx = t; idx < 2048; idx += 256) {
        int jw = idx & 3, lane = (idx >> 2) & 63, n = idx >> 8;
        int i0 = 8 * (lane >> 4) + 2 * jw;   // GEMM K index (channel i)
        int km = n * 16 + (lane & 15);       // MLP hidden index
        float we = w0[i0 * 128 + km], wo = w0[(i0 + 1) * 128 + km];
        unsigned ue = __float_as_uint(we), uo = __float_as_uint(wo);
        wB[idx] = ((uo >> 16) << 16) | (ue >> 16);
        float re = we - __uint_as_float(ue & 0xffff0000u);
        float ro = wo - __uint_as_float(uo & 0xffff0000u);
        wB[2048 + idx] = ((__float_as_uint(ro) >> 16) << 16)
                       | (__float_as_uint(re) >> 16);
    }
    for (int idx = t; idx < 384; idx += 256) {
        int c = idx >> 7, km = idx & 127;
        w1p[idx] = w1[km * 3 + c];
    }
}

// Lift + ky-forward DFT for layer 0.
__global__ __launch_bounds__(256, 4) void k_liftf(const float* __restrict__ xin,
                                                  const float* __restrict__ pw,
                                                  const float* __restrict__ pb,
                                                  float* __restrict__ h,
                                                  float* __restrict__ tmp) {
    __shared__ float sVp[32 * 258];
    __shared__ float2 sCSP[256];
    int b = blockIdx.x >> 8, x = blockIdx.x & 255, y = threadIdx.x;
    fill_csp(sCSP, y, 256);
    int vslot = 2 * ((y <= 128) ? y : 256 - y) + ((y > 128) ? 1 : 0);
    float f0 = xin[((b * 3 + 0) * 256 + x) * 256 + y];
    float f1 = xin[((b * 3 + 1) * 256 + x) * 256 + y];
    float f2 = xin[((b * 3 + 2) * 256 + x) * 256 + y];
    float gx = x * (1.0f / 255.0f), gy = y * (1.0f / 255.0f);
#pragma unroll
    for (int o = 0; o < 32; ++o) {
        float v = pb[o] + f0 * pw[o] + f1 * pw[32 + o] + f2 * pw[64 + o]
                + gx * pw[96 + o] + gy * pw[128 + o];
        h[((b * 32 + o) * 256 + x) * 256 + y] = v;
        sVp[o * 258 + vslot] = v;
    }
    __syncthreads();
    ky_dft_tail(sVp, sCSP, tmp, b, x, y);
}

// kx-forward DFT (4-way x-split): hfp[part][plane][kxi][ky]
__global__ __launch_bounds__(320) void k_dftx(const float* __restrict__ tmp,
                                              float* __restrict__ hfp) {
    __shared__ float sT[1536];
    __shared__ float2 sCSP[256];
    int plane = blockIdx.x >> 2, part = blockIdx.x & 3;
    int x0 = part * 64;
    int tid = threadIdx.x;
    fill_csp(sCSP, tid, 320);
    for (int idx = tid; idx < 1536; idx += 320)
        sT[idx] = tmp[(size_t)plane * 6144 + x0 * 24 + idx];
    __syncthreads();
    if (tid < 288) {
        int kxi = tid / 12, ky = tid % 12;
        int kxv = kxi < 12 ? kxi : 232 + kxi;
        float aR = 0.f, aI = 0.f;
        for (int xp = 0; xp < 64; ++xp) {
            int p = (kxv * (x0 + xp)) & 255;
            float2 cs2 = sCSP[p];
            float tr = sT[xp * 24 + 2 * ky], ti = sT[xp * 24 + 2 * ky + 1];
            aR += tr * cs2.x + ti * cs2.y;
            aI += ti * cs2.x - tr * cs2.y;
        }
        hfp[(((size_t)part * 128 + plane) * 24 + kxi) * 24 + 2 * ky]     = aR;
        hfp[(((size_t)part * 128 + plane) * 24 + kxi) * 24 + 2 * ky + 1] = aI;
    }
}

// Mode mix + kx-inverse, one block per (b,o).
__global__ __launch_bounds__(320) void k_mixcinv(const float* __restrict__ hfp,
                                                 const float* __restrict__ w1r,
                                                 const float* __restrict__ w1i,
                                                 const float* __restrict__ w2r,
                                                 const float* __restrict__ w2i,
                                                 float* __restrict__ g, int l) {
    __shared__ float sA[576];
    __shared__ float2 sCSP[256];
    int b = blockIdx.x >> 5, o = blockIdx.x & 31;
    int tid = threadIdx.x;
    fill_csp(sCSP, tid, 320);
    if (tid < 288) {
        int kxi = tid / 12, ky = tid % 12;
        const float *wr, *wi;
        int rk;
        if (kxi < 12) { wr = w1r; wi = w1i; rk = kxi; }
        else          { wr = w2r; wi = w2i; rk = kxi - 12; }
        size_t wbase = ((size_t)l * 32 * 32) * 144 + (size_t)o * 144 + rk * 12 + ky;
        size_t hbase = (((size_t)(b * 32)) * 24 + kxi) * 24 + 2 * ky;
        float aR = 0.f, aI = 0.f;
#pragma unroll 4
        for (int i = 0; i < 32; ++i) {
            float2 h0 = *reinterpret_cast<const float2*>(hfp + hbase + i * 576);
            float2 h1 = *reinterpret_cast<const float2*>(hfp + 73728 + hbase + i * 576);
            float2 h2 = *reinterpret_cast<const float2*>(hfp + 147456 + hbase + i * 576);
            float2 h3 = *reinterpret_cast<const float2*>(hfp + 221184 + hbase + i * 576);
            float hr = h0.x + h1.x + h2.x + h3.x;
            float hi = h0.y + h1.y + h2.y + h3.y;
            float wrv = wr[wbase + (size_t)i * 4608];
            float wiv = wi[wbase + (size_t)i * 4608];
            aR += hr * wrv - hi * wiv;
            aI += hr * wiv + hi * wrv;
        }
        sA[kxi * 24 + 2 * ky]     = aR;
        sA[kxi * 24 + 2 * ky + 1] = aI;
    }
    __syncthreads();
    if (tid < 256) {
        int x = tid;
        float out[24];
#pragma unroll
        for (int j = 0; j < 24; ++j) out[j] = 0.f;
        for (int kxi = 0; kxi < 24; ++kxi) {
            int kxv = kxi < 12 ? kxi : 232 + kxi;
            int p = (kxv * x) & 255;
            float2 cs2 = sCSP[p];
#pragma unroll
            for (int ky = 0; ky < 12; ++ky) {
                float ar = sA[kxi * 24 + 2 * ky], ai = sA[kxi * 24 + 2 * ky + 1];
                out[2 * ky]     += ar * cs2.x - ai * cs2.y;
                out[2 * ky + 1] += ar * cs2.y + ai * cs2.x;
            }
        }
        float* gp = g + ((size_t)(b * 32 + o)) * 6144 + x * 24;
#pragma unroll
        for (int j = 0; j < 24; ++j) gp[j] = out[j];
    }
}

// Layers 0..2: bypass+spectral+gelu, in-place h, + next-layer ky-DFT.
__attribute__((amdgpu_waves_per_eu(2, 4)))
__global__ __launch_bounds__(256) void k_dinvf(float* __restrict__ h,
                                               const float* __restrict__ g,
                                               const float* __restrict__ cwp,
                                               float* __restrict__ tmp,
                                               int l) {
    __shared__ float sVp[32 * 258];
    __shared__ float2 sCSP[256];
    __shared__ float sG[768];
    int b = blockIdx.x >> 8, x = blockIdx.x & 255;
    int y = threadIdx.x;
    fill_csp(sCSP, y, 256);
    for (int idx = y; idx < 768; idx += 256) {
        int o = idx / 24, j = idx - o * 24;
        sG[idx] = g[(((size_t)(b * 32 + o)) * 256 + x) * 24 + j];
    }
    int vslot = 2 * ((y <= 128) ? y : 256 - y) + ((y > 128) ? 1 : 0);
    float hreg[32];
#pragma unroll
    for (int i = 0; i < 32; ++i)
        hreg[i] = h[(((size_t)(b * 32 + i)) * 256 + x) * 256 + y];
    __syncthreads();
    float ck[12], sk[12];
#pragma unroll
    for (int ky = 1; ky < 12; ++ky) {
        int p = (ky * y) & 255;
        float2 cs2 = sCSP[p];
        ck[ky] = 2.0f * cs2.x; sk[ky] = 2.0f * cs2.y;
    }
    const float* wb = cwp + l * 32 * 36;
    for (int o = 0; o < 32; ++o) {
        const float* gp = sG + o * 24;             // LDS broadcast reads
        const float* wp = wb + o * 36;             // uniform (scalar) address
        float sc0 = gp[0], sc1 = 0.f, ss0 = 0.f, ss1 = 0.f;
#pragma unroll
        for (int ky = 1; ky < 12; ky += 2) {
            sc0 = __builtin_fmaf(gp[2 * ky], ck[ky], sc0);
            ss0 = __builtin_fmaf(gp[2 * ky + 1], sk[ky], ss0);
        }
#pragma unroll
        for (int ky = 2; ky < 12; ky += 2) {
            sc1 = __builtin_fmaf(gp[2 * ky], ck[ky], sc1);
            ss1 = __builtin_fmaf(gp[2 * ky + 1], sk[ky], ss1);
        }
        float spec = (sc0 + sc1) - (ss0 + ss1);
        float va0 = __builtin_fmaf(spec, 1.0f / 65536.0f, wp[32]);
        float va1 = 0.f, va2 = 0.f, va3 = 0.f;
#pragma unroll
        for (int i = 0; i < 32; i += 4) {
            va0 = __builtin_fmaf(hreg[i],     wp[i],     va0);
            va1 = __builtin_fmaf(hreg[i + 1], wp[i + 1], va1);
            va2 = __builtin_fmaf(hreg[i + 2], wp[i + 2], va2);
            va3 = __builtin_fmaf(hreg[i + 3], wp[i + 3], va3);
        }
        float v = (va0 + va1) + (va2 + va3);
        v = fgelu(v);
        h[(((size_t)(b * 32 + o)) * 256 + x) * 256 + y] = v;
        sVp[o * 258 + vslot] = v;
    }
    __syncthreads();
    ky_dft_tail(sVp, sCSP, tmp, b, x, y);
}

// Layer 3 (no gelu, no DFT) fused with the final MLP; h never written.
// Phase A: R8 config (scalar g + scalar weights, sCSP table, vcol to sVv).
// Phase B: MFMA GEMM, split-bf16 3-pass. Wave w owns rows [64w, 64w+64).
__global__ __launch_bounds__(256) void k_dinvmlp(const float* __restrict__ h,
                                                 const float* __restrict__ g,
                                                 const float* __restrict__ cwp,
                                                 const float* __restrict__ wpk,
                                                 const unsigned* __restrict__ wB,
                                                 const float* __restrict__ b0,
                                                 const float* __restrict__ w1p,
                                                 float* __restrict__ out) {
    __shared__ float sVv[256 * 33];
    __shared__ float2 sCSP[256];
    int b = blockIdx.x >> 8, x = blockIdx.x & 255;
    int y = threadIdx.x;
    fill_csp(sCSP, y, 256);
    float hreg[32];
#pragma unroll
    for (int i = 0; i < 32; ++i)
        hreg[i] = h[(((size_t)(b * 32 + i)) * 256 + x) * 256 + y];
    __syncthreads();
    float ck[12], sk[12];
#pragma unroll
    for (int ky = 1; ky < 12; ++ky) {
        int p = (ky * y) & 255;
        float2 cs2 = sCSP[p];
        ck[ky] = 2.0f * cs2.x; sk[ky] = 2.0f * cs2.y;
    }
    const float* gb = g + ((size_t)(b * 32) * 256 + x) * 24;
    const float* wb = cwp + 3 * 32 * 36;
    float* vcol = sVv + y * 33;
    for (int o = 0; o < 32; ++o) {
        const float* gp = gb + (size_t)o * 6144;   // uniform address
        const float* wp = wb + o * 36;             // uniform address
        float sc0 = gp[0], sc1 = 0.f, ss0 = 0.f, ss1 = 0.f;
#pragma unroll
        for (int ky = 1; ky < 12; ky += 2) {
            sc0 = __builtin_fmaf(gp[2 * ky], ck[ky], sc0);
            ss0 = __builtin_fmaf(gp[2 * ky + 1], sk[ky], ss0);
        }
#pragma unroll
        for (int ky = 2; ky < 12; ky += 2) {
            sc1 = __builtin_fmaf(gp[2 * ky], ck[ky], sc1);
            ss1 = __builtin_fmaf(gp[2 * ky + 1], sk[ky], ss1);
        }
        float spec = (sc0 + sc1) - (ss0 + ss1);
        float va0 = __builtin_fmaf(spec, 1.0f / 65536.0f, wp[32]);
        float va1 = 0.f, va2 = 0.f, va3 = 0.f;
#pragma unroll
        for (int i = 0; i < 32; i += 4) {
            va0 = __builtin_fmaf(hreg[i],     wp[i],     va0);
            va1 = __builtin_fmaf(hreg[i + 1], wp[i + 1], va1);
            va2 = __builtin_fmaf(hreg[i + 2], wp[i + 2], va2);
            va3 = __builtin_fmaf(hreg[i + 3], wp[i + 3], va3);
        }
        vcol[o] = (va0 + va1) + (va2 + va3);   // v[y][o] -> sVv
    }
    __syncthreads();   // phase B reads other threads' columns

    // ---- Phase B: T = V @ W0 (MFMA), gelu, apart += t * W1 ----
    int wv = y >> 6, lane = y & 63;
    bf16x8_t Ahi[4], Alo[4];
    {
        const float* ab = sVv + ((wv << 6) + (lane & 15)) * 33 + ((lane >> 4) << 3);
#pragma unroll
        for (int mt = 0; mt < 4; ++mt) {
            const float* ap = ab + mt * 16 * 33;
#pragma unroll
            for (int j = 0; j < 8; ++j) {
                float v = ap[j];
                unsigned u = __float_as_uint(v);
                Ahi[mt][j] = (short)(u >> 16);
                float r = v - __uint_as_float(u & 0xffff0000u);
                Alo[mt][j] = (short)(__float_as_uint(r) >> 16);
            }
        }
    }
    float apart[4][4][3];
#pragma unroll
    for (int mt = 0; mt < 4; ++mt)
#pragma unroll
        for (int r = 0; r < 4; ++r)
#pragma unroll
            for (int c = 0; c < 3; ++c) apart[mt][r][c] = 0.f;

    for (int n = 0; n < 8; ++n) {
        bf16x8_t Bhi = *reinterpret_cast<const bf16x8_t*>(wB + (n * 64 + lane) * 4);
        bf16x8_t Blo = *reinterpret_cast<const bf16x8_t*>(wB + 2048 + (n * 64 + lane) * 4);
        int km = (n << 4) + (lane & 15);
        float b0v  = b0[km];
        float w1v0 = w1p[km], w1v1 = w1p[128 + km], w1v2 = w1p[256 + km];
#pragma unroll
        for (int mt = 0; mt < 4; ++mt) {
            f32x4_t acc = {0.f, 0.f, 0.f, 0.f};
            acc = __builtin_amdgcn_mfma_f32_16x16x32_bf16(Ahi[mt], Bhi, acc, 0, 0, 0);
            acc = __builtin_amdgcn_mfma_f32_16x16x32_bf16(Ahi[mt], Blo, acc, 0, 0, 0);
            acc = __builtin_amdgcn_mfma_f32_16x16x32_bf16(Alo[mt], Bhi, acc, 0, 0, 0);
#pragma unroll
            for (int r = 0; r < 4; ++r) {
                float tg = fgelu(acc[r] + b0v);
                apart[mt][r][0] = __builtin_fmaf(tg, w1v0, apart[mt][r][0]);
                apart[mt][r][1] = __builtin_fmaf(tg, w1v1, apart[mt][r][1]);
                apart[mt][r][2] = __builtin_fmaf(tg, w1v2, apart[mt][r][2]);
            }
        }
    }
    // Reduce over the 16 k-lanes of each row-group; write via sVv (dead now).
#pragma unroll
    for (int mt = 0; mt < 4; ++mt)
#pragma unroll
        for (int r = 0; r < 4; ++r)
#pragma unroll
            for (int c = 0; c < 3; ++c) {
                float v = apart[mt][r][c];
                v += __shfl_xor(v, 1);
                v += __shfl_xor(v, 2);
                v += __shfl_xor(v, 4);
                v += __shfl_xor(v, 8);
                if ((lane & 15) == 0)
                    sVv[((wv << 6) + (mt << 4) + ((lane >> 4) << 2) + r) * 33 + c] = v;
            }
    __syncthreads();
    float b1v0 = wpk[4608], b1v1 = wpk[4609], b1v2 = wpk[4610];
    out[(((size_t)b * 3 + 0) * 256 + x) * 256 + y] = sVv[y * 33 + 0] + b1v0;
    out[(((size_t)b * 3 + 1) * 256 + x) * 256 + y] = sVv[y * 33 + 1] + b1v1;
    out[(((size_t)b * 3 + 2) * 256 + x) * 256 + y] = sVv[y * 33 + 2] + b1v2;
}

extern "C" void kernel_launch(void* const* d_in, const int* in_sizes, int n_in,
                              void* d_out, int out_size, void* d_ws, size_t ws_size,
                              hipStream_t stream) {
    const float* xin  = (const float*)d_in[0];
    const float* pw   = (const float*)d_in[1];
    const float* pb   = (const float*)d_in[2];
    const float* sw1r = (const float*)d_in[3];
    const float* sw1i = (const float*)d_in[4];
    const float* sw2r = (const float*)d_in[5];
    const float* sw2i = (const float*)d_in[6];
    const float* cw   = (const float*)d_in[7];
    const float* cb   = (const float*)d_in[8];
    const float* w0   = (const float*)d_in[9];
    const float* b0   = (const float*)d_in[10];
    const float* w1   = (const float*)d_in[11];
    const float* b1   = (const float*)d_in[12];
    float* out = (float*)d_out;

    float* ws  = (float*)d_ws;
    float* wpk = ws;                           // 4624
    float* cwp = wpk + 4624;                   // 4608
    unsigned* wB = (unsigned*)(cwp + 4608);    // 4096 u32
    float* w1p = (float*)(wB + 4096);          // 384
    float* h   = w1p + 384;                    // 8388608
    float* tmp = h + 8388608;                  // 786432 (aliased with g)
    float* hfp = tmp + 786432;                 // 294912
    float* g   = tmp;                          // alias

    k_init<<<1, 256, 0, stream>>>(w0, b0, w1, b1, cw, cb, wpk, cwp, wB, w1p);
    k_liftf<<<1024, 256, 0, stream>>>(xin, pw, pb, h, tmp);
    for (int l = 0; l < 4; ++l) {
        k_dftx<<<512, 320, 0, stream>>>(tmp, hfp);
        k_mixcinv<<<128, 320, 0, stream>>>(hfp, sw1r, sw1i, sw2r, sw2i, g, l);
        if (l < 3)
            k_dinvf<<<1024, 256, 0, stream>>>(h, g, cwp, tmp, l);
        else
            k_dinvmlp<<<1024, 256, 0, stream>>>(h, g, cwp, wpk, wB, b0, w1p, out);
    }
}

// Round 13
// 215.879 us; speedup vs baseline: 1.4933x; 1.3451x over previous
//
#include <hip/hip_runtime.h>
#include <math.h>

// FNO2d: B=4, C=3, H=W=256, L=4, WIDTH=32, M1=M2=12
// R13: full-MFMA dinv layers. Per (b,x) block, three GEMMs on the matrix pipe
// (split-bf16 3-pass, layouts HW-verified in R11):
//   spec   = C2[256x24] @ (g/65536)[24x32]   (C2 static table -> no g s_load chain)
//   bypass = H[256x32] @ CW[32x32]           (accumulated into same acc)
//   tail   = E[24x256] @ V[256x32]           (ky-forward DFT for next layer)
// V crosses phases via LDS sVvT[o][y] as packed (bf16hi<<16|bf16lo) u32.
// g aliases tmp: g read pre-barrier, tmp written post-barrier, disjoint x.
// dinvmlp = same phase A (no gelu) + R11 MFMA MLP phase B.
//
// ws layout (u32/floats):
//   specA [8192 u32] : C2 A-frags (hi 0..4095, lo 4096..)
//   tailA [8192 u32] : E A-frags  (hi, lo)
//   cwB   [4096 u32] : CW B-frags per layer (hi 0..2047, lo 2048..)
//   wB    [4096 u32] : MLP W0 B-frags (hi, lo)
//   w1p   [384 f32]  : W1 column-major [c][k]
//   h     [8388608]  : activations (B,32,H,W), in place per layer
//   tmp   [786432]   : ky-DFT out (B,32,H,12) complex; ALIASED with g
//   hfp   [294912]   : 4 x-partials of (B,32,24,12) complex

#define ANG0 0.024543692606170260f  // 2*pi/256

typedef __attribute__((ext_vector_type(8))) short bf16x8_t;
typedef __attribute__((ext_vector_type(4))) float f32x4_t;

__device__ __forceinline__ float fgelu(float v) {
    // exact-GELU via A&S 7.1.26 erf approx, |err| <= 1.5e-7, branchless
    float u = v * 0.70710678118f;
    float a = fabsf(u);
    float t = __builtin_amdgcn_rcpf(__builtin_fmaf(0.3275911f, a, 1.0f));
    float p = t * __builtin_fmaf(t, __builtin_fmaf(t, __builtin_fmaf(t,
                  __builtin_fmaf(t, 1.061405429f, -1.453152027f),
                  1.421413741f), -0.284496736f), 0.254829592f);
    float e = __expf(-u * u);
    float er = __builtin_fmaf(-p, e, 1.0f);
    er = copysignf(er, u);
    return 0.5f * v * (1.0f + er);
}

__device__ __forceinline__ unsigned packsplit(float v) {
    unsigned u = __float_as_uint(v);
    unsigned hi = u & 0xffff0000u;
    float r = v - __uint_as_float(hi);
    return hi | (__float_as_uint(r) >> 16);
}

__device__ __forceinline__ void fill_csp(float2* sCSP, int tid, int nthr) {
    for (int p = tid; p < 256; p += nthr)
        sCSP[p] = make_float2(cosf(p * ANG0), sinf(p * ANG0));
}

// ky-forward DFT (fp32, liftf only), pair-packed sVp layout.
__device__ __forceinline__ void ky_dft_tail(const float* sVp, const float2* sCSP,
                                            float* tmp, int b, int x, int y) {
    for (int idx = y; idx < 384; idx += 256) {
        int o = idx / 12, ky = idx % 12;
        const float* vp = sVp + o * 258;
        float vdc = vp[0], v128 = vp[256];
        float aR0 = vdc + ((ky & 1) ? -v128 : v128);
        float aR1 = 0.f, aI0 = 0.f, aI1 = 0.f;
#pragma unroll 4
        for (int yy = 1; yy <= 126; yy += 2) {
            int p0 = (ky * yy) & 255;
            int p1 = (p0 + ky) & 255;
            float2 c0 = sCSP[p0], c1 = sCSP[p1];
            float2 v0 = *reinterpret_cast<const float2*>(vp + 2 * yy);
            float2 v1 = *reinterpret_cast<const float2*>(vp + 2 * (yy + 1));
            aR0 = __builtin_fmaf(v0.x + v0.y, c0.x, aR0);
            aI0 = __builtin_fmaf(v0.x - v0.y, -c0.y, aI0);
            aR1 = __builtin_fmaf(v1.x + v1.y, c1.x, aR1);
            aI1 = __builtin_fmaf(v1.x - v1.y, -c1.y, aI1);
        }
        {
            int p = (ky * 127) & 255;
            float2 c = sCSP[p];
            float2 v0 = *reinterpret_cast<const float2*>(vp + 254);
            aR0 = __builtin_fmaf(v0.x + v0.y, c.x, aR0);
            aI0 = __builtin_fmaf(v0.x - v0.y, -c.y, aI0);
        }
        reinterpret_cast<float2*>(tmp + (((size_t)(b * 32 + o)) * 256 + x) * 24)[ky] =
            make_float2(aR0 + aR1, aI0 + aI1);
    }
}

__device__ __forceinline__ float c2val(int y, int j) {
    if (j >= 24 || j == 1) return 0.f;
    if (j == 0) return 1.f;
    int q = j >> 1;
    float ang = ((q * y) & 255) * ANG0;
    return (j & 1) ? -2.f * sinf(ang) : 2.f * cosf(ang);
}
__device__ __forceinline__ float etval(int j, int y) {
    if (j >= 24) return 0.f;
    int q = j >> 1;
    float ang = ((q * y) & 255) * ANG0;
    return (j & 1) ? -sinf(ang) : cosf(ang);
}
__device__ __forceinline__ void pack2(unsigned* dsthi, unsigned* dstlo,
                                      float v0, float v1) {
    unsigned u0 = __float_as_uint(v0), u1 = __float_as_uint(v1);
    *dsthi = ((u1 >> 16) << 16) | (u0 >> 16);
    float r0 = v0 - __uint_as_float(u0 & 0xffff0000u);
    float r1 = v1 - __uint_as_float(u1 & 0xffff0000u);
    *dstlo = ((__float_as_uint(r1) >> 16) << 16) | (__float_as_uint(r0) >> 16);
}

__global__ void k_init(const float* __restrict__ w0, const float* __restrict__ b0,
                       const float* __restrict__ w1, const float* __restrict__ cw,
                       unsigned* __restrict__ specA, unsigned* __restrict__ tailA,
                       unsigned* __restrict__ cwB, unsigned* __restrict__ wB,
                       float* __restrict__ w1p) {
    int t = threadIdx.x;
    for (int idx = t; idx < 4096; idx += 256) {   // specA: C2[y][j] A-frags
        int w = idx & 3, lane = (idx >> 2) & 63, mt = idx >> 8;
        int y = mt * 16 + (lane & 15);
        int j0 = 8 * (lane >> 4) + 2 * w;
        pack2(&specA[idx], &specA[4096 + idx], c2val(y, j0), c2val(y, j0 + 1));
    }
    for (int idx = t; idx < 4096; idx += 256) {   // tailA: E[j][y] A-frags
        int w = idx & 3, lane = (idx >> 2) & 63, tt = idx >> 8;
        int kk = tt >> 1, mtj = tt & 1;
        int j = mtj * 16 + (lane & 15);
        int y0 = kk * 32 + 8 * (lane >> 4) + 2 * w;
        pack2(&tailA[idx], &tailA[4096 + idx], etval(j, y0), etval(j, y0 + 1));
    }
    for (int idx = t; idx < 2048; idx += 256) {   // cwB: CW[i][o] B-frags
        int w = idx & 3, lane = (idx >> 2) & 63, tt = idx >> 8;
        int l = tt >> 1, n = tt & 1;
        int o = n * 16 + (lane & 15);
        int i0 = 8 * (lane >> 4) + 2 * w;
        pack2(&cwB[idx], &cwB[2048 + idx],
              cw[l * 1024 + i0 * 32 + o], cw[l * 1024 + (i0 + 1) * 32 + o]);
    }
    for (int idx = t; idx < 2048; idx += 256) {   // wB: W0 B-frags (as R11)
        int jw = idx & 3, lane = (idx >> 2) & 63, n = idx >> 8;
        int i0 = 8 * (lane >> 4) + 2 * jw;
        int km = n * 16 + (lane & 15);
        pack2(&wB[idx], &wB[2048 + idx], w0[i0 * 128 + km], w0[(i0 + 1) * 128 + km]);
    }
    for (int idx = t; idx < 384; idx += 256) {
        int c = idx >> 7, km = idx & 127;
        w1p[idx] = w1[km * 3 + c];
    }
}

// Lift + ky-forward DFT for layer 0 (unchanged fp32 path).
__global__ __launch_bounds__(256, 4) void k_liftf(const float* __restrict__ xin,
                                                  const float* __restrict__ pw,
                                                  const float* __restrict__ pb,
                                                  float* __restrict__ h,
                                                  float* __restrict__ tmp) {
    __shared__ float sVp[32 * 258];
    __shared__ float2 sCSP[256];
    int b = blockIdx.x >> 8, x = blockIdx.x & 255, y = threadIdx.x;
    fill_csp(sCSP, y, 256);
    int vslot = 2 * ((y <= 128) ? y : 256 - y) + ((y > 128) ? 1 : 0);
    float f0 = xin[((b * 3 + 0) * 256 + x) * 256 + y];
    float f1 = xin[((b * 3 + 1) * 256 + x) * 256 + y];
    float f2 = xin[((b * 3 + 2) * 256 + x) * 256 + y];
    float gx = x * (1.0f / 255.0f), gy = y * (1.0f / 255.0f);
#pragma unroll
    for (int o = 0; o < 32; ++o) {
        float v = pb[o] + f0 * pw[o] + f1 * pw[32 + o] + f2 * pw[64 + o]
                + gx * pw[96 + o] + gy * pw[128 + o];
        h[((b * 32 + o) * 256 + x) * 256 + y] = v;
        sVp[o * 258 + vslot] = v;
    }
    __syncthreads();
    ky_dft_tail(sVp, sCSP, tmp, b, x, y);
}

// kx-forward DFT (4-way x-split): hfp[part][plane][kxi][ky]  (unchanged)
__global__ __launch_bounds__(320) void k_dftx(const float* __restrict__ tmp,
                                              float* __restrict__ hfp) {
    __shared__ float sT[1536];
    __shared__ float2 sCSP[256];
    int plane = blockIdx.x >> 2, part = blockIdx.x & 3;
    int x0 = part * 64;
    int tid = threadIdx.x;
    fill_csp(sCSP, tid, 320);
    for (int idx = tid; idx < 1536; idx += 320)
        sT[idx] = tmp[(size_t)plane * 6144 + x0 * 24 + idx];
    __syncthreads();
    if (tid < 288) {
        int kxi = tid / 12, ky = tid % 12;
        int kxv = kxi < 12 ? kxi : 232 + kxi;
        float aR = 0.f, aI = 0.f;
        for (int xp = 0; xp < 64; ++xp) {
            int p = (kxv * (x0 + xp)) & 255;
            float2 cs2 = sCSP[p];
            float tr = sT[xp * 24 + 2 * ky], ti = sT[xp * 24 + 2 * ky + 1];
            aR += tr * cs2.x + ti * cs2.y;
            aI += ti * cs2.x - tr * cs2.y;
        }
        hfp[(((size_t)part * 128 + plane) * 24 + kxi) * 24 + 2 * ky]     = aR;
        hfp[(((size_t)part * 128 + plane) * 24 + kxi) * 24 + 2 * ky + 1] = aI;
    }
}

// Mode mix + kx-inverse, one block per (b,o).  (unchanged)
__global__ __launch_bounds__(320) void k_mixcinv(const float* __restrict__ hfp,
                                                 const float* __restrict__ w1r,
                                                 const float* __restrict__ w1i,
                                                 const float* __restrict__ w2r,
                                                 const float* __restrict__ w2i,
                                                 float* __restrict__ g, int l) {
    __shared__ float sA[576];
    __shared__ float2 sCSP[256];
    int b = blockIdx.x >> 5, o = blockIdx.x & 31;
    int tid = threadIdx.x;
    fill_csp(sCSP, tid, 320);
    if (tid < 288) {
        int kxi = tid / 12, ky = tid % 12;
        const float *wr, *wi;
        int rk;
        if (kxi < 12) { wr = w1r; wi = w1i; rk = kxi; }
        else          { wr = w2r; wi = w2i; rk = kxi - 12; }
        size_t wbase = ((size_t)l * 32 * 32) * 144 + (size_t)o * 144 + rk * 12 + ky;
        size_t hbase = (((size_t)(b * 32)) * 24 + kxi) * 24 + 2 * ky;
        float aR = 0.f, aI = 0.f;
#pragma unroll 4
        for (int i = 0; i < 32; ++i) {
            float2 h0 = *reinterpret_cast<const float2*>(hfp + hbase + i * 576);
            float2 h1 = *reinterpret_cast<const float2*>(hfp + 73728 + hbase + i * 576);
            float2 h2 = *reinterpret_cast<const float2*>(hfp + 147456 + hbase + i * 576);
            float2 h3 = *reinterpret_cast<const float2*>(hfp + 221184 + hbase + i * 576);
            float hr = h0.x + h1.x + h2.x + h3.x;
            float hi = h0.y + h1.y + h2.y + h3.y;
            float wrv = wr[wbase + (size_t)i * 4608];
            float wiv = wi[wbase + (size_t)i * 4608];
            aR += hr * wrv - hi * wiv;
            aI += hr * wiv + hi * wrv;
        }
        sA[kxi * 24 + 2 * ky]     = aR;
        sA[kxi * 24 + 2 * ky + 1] = aI;
    }
    __syncthreads();
    if (tid < 256) {
        int x = tid;
        float out[24];
#pragma unroll
        for (int j = 0; j < 24; ++j) out[j] = 0.f;
        for (int kxi = 0; kxi < 24; ++kxi) {
            int kxv = kxi < 12 ? kxi : 232 + kxi;
            int p = (kxv * x) & 255;
            float2 cs2 = sCSP[p];
#pragma unroll
            for (int ky = 0; ky < 12; ++ky) {
                float ar = sA[kxi * 24 + 2 * ky], ai = sA[kxi * 24 + 2 * ky + 1];
                out[2 * ky]     += ar * cs2.x - ai * cs2.y;
                out[2 * ky + 1] += ar * cs2.y + ai * cs2.x;
            }
        }
        float* gp = g + ((size_t)(b * 32 + o)) * 6144 + x * 24;
#pragma unroll
        for (int j = 0; j < 24; ++j) gp[j] = out[j];
    }
}

// Shared phase A: spec+bypass GEMMs into packed sVvT. ACT: apply gelu.
template <int ACT>
__device__ __forceinline__ void dinv_phaseA(const float* __restrict__ h,
                                            const float* __restrict__ g,
                                            const unsigned* __restrict__ specA,
                                            const unsigned* __restrict__ cwB,
                                            const float* __restrict__ cb,
                                            unsigned* sVvT, int b, int x, int l,
                                            int wv, int lane) {
    int l15 = lane & 15, l4 = lane >> 4;
    // G B-fragments (both n-tiles), scaled 1/65536, split hi/lo.
    bf16x8_t Ghi[2], Glo[2];
#pragma unroll
    for (int n = 0; n < 2; ++n) {
        float gv[8];
        if (l4 < 3) {
            const float* gp = g + (size_t)(b * 32 + n * 16 + l15) * 6144
                            + x * 24 + 8 * l4;
            float4 a = *reinterpret_cast<const float4*>(gp);
            float4 c = *reinterpret_cast<const float4*>(gp + 4);
            gv[0] = a.x; gv[1] = a.y; gv[2] = a.z; gv[3] = a.w;
            gv[4] = c.x; gv[5] = c.y; gv[6] = c.z; gv[7] = c.w;
        } else {
#pragma unroll
            for (int j = 0; j < 8; ++j) gv[j] = 0.f;
        }
#pragma unroll
        for (int j = 0; j < 8; ++j) {
            float v = gv[j] * (1.0f / 65536.0f);
            unsigned u = __float_as_uint(v);
            Ghi[n][j] = (short)(u >> 16);
            float r = v - __uint_as_float(u & 0xffff0000u);
            Glo[n][j] = (short)(__float_as_uint(r) >> 16);
        }
    }
    bf16x8_t Whi[2], Wlo[2];
#pragma unroll
    for (int n = 0; n < 2; ++n) {
        Whi[n] = *reinterpret_cast<const bf16x8_t*>(cwB + ((l * 2 + n) * 64 + lane) * 4);
        Wlo[n] = *reinterpret_cast<const bf16x8_t*>(cwB + 2048 + ((l * 2 + n) * 64 + lane) * 4);
    }
    float cbb[2] = {cb[l * 32 + l15], cb[l * 32 + 16 + l15]};
#pragma unroll
    for (int mtl = 0; mtl < 4; ++mtl) {
        int mtg = wv * 4 + mtl;
        bf16x8_t C2hi = *reinterpret_cast<const bf16x8_t*>(specA + (mtg * 64 + lane) * 4);
        bf16x8_t C2lo = *reinterpret_cast<const bf16x8_t*>(specA + 4096 + (mtg * 64 + lane) * 4);
        bf16x8_t Hhi, Hlo;
        {
            const float* hp = h + (size_t)(b * 32) * 65536 + x * 256 + mtg * 16 + l15;
#pragma unroll
            for (int j = 0; j < 8; ++j) {
                float v = hp[(size_t)(8 * l4 + j) * 65536];
                unsigned u = __float_as_uint(v);
                Hhi[j] = (short)(u >> 16);
                float r = v - __uint_as_float(u & 0xffff0000u);
                Hlo[j] = (short)(__float_as_uint(r) >> 16);
            }
        }
#pragma unroll
        for (int n = 0; n < 2; ++n) {
            f32x4_t acc = {0.f, 0.f, 0.f, 0.f};
            acc = __builtin_amdgcn_mfma_f32_16x16x32_bf16(C2hi, Ghi[n], acc, 0, 0, 0);
            acc = __builtin_amdgcn_mfma_f32_16x16x32_bf16(C2lo, Ghi[n], acc, 0, 0, 0);
            acc = __builtin_amdgcn_mfma_f32_16x16x32_bf16(C2hi, Glo[n], acc, 0, 0, 0);
            acc = __builtin_amdgcn_mfma_f32_16x16x32_bf16(Hhi, Whi[n], acc, 0, 0, 0);
            acc = __builtin_amdgcn_mfma_f32_16x16x32_bf16(Hlo, Whi[n], acc, 0, 0, 0);
            acc = __builtin_amdgcn_mfma_f32_16x16x32_bf16(Hhi, Wlo[n], acc, 0, 0, 0);
            uint4 pu;
            {
                float v0 = acc[0] + cbb[n], v1 = acc[1] + cbb[n];
                float v2 = acc[2] + cbb[n], v3 = acc[3] + cbb[n];
                if (ACT) { v0 = fgelu(v0); v1 = fgelu(v1); v2 = fgelu(v2); v3 = fgelu(v3); }
                pu.x = packsplit(v0); pu.y = packsplit(v1);
                pu.z = packsplit(v2); pu.w = packsplit(v3);
            }
            *reinterpret_cast<uint4*>(&sVvT[(n * 16 + l15) * 260 + mtg * 16 + l4 * 4]) = pu;
        }
    }
}

// Layers 0..2: MFMA spec+bypass+gelu, h write, MFMA ky-DFT tail.
__global__ __launch_bounds__(256) void k_dinvf(float* __restrict__ h,
                                               const float* __restrict__ g,
                                               const unsigned* __restrict__ specA,
                                               const unsigned* __restrict__ tailA,
                                               const unsigned* __restrict__ cwB,
                                               const float* __restrict__ cb,
                                               float* __restrict__ tmp, int l) {
    __shared__ unsigned sVvT[32 * 260];
    int b = blockIdx.x >> 8, x = blockIdx.x & 255;
    int tid = threadIdx.x, wv = tid >> 6, lane = tid & 63;
    int l15 = lane & 15, l4 = lane >> 4;
    dinv_phaseA<1>(h, g, specA, cwB, cb, sVvT, b, x, l, wv, lane);
    __syncthreads();
    // h write (coalesced): reconstruct fp32 = bf(hi) + bf(lo).
    {
        size_t hb = (size_t)(b * 32) * 65536 + x * 256 + tid;
#pragma unroll 8
        for (int o = 0; o < 32; ++o) {
            unsigned u = sVvT[o * 260 + tid];
            h[hb + (size_t)o * 65536] =
                __uint_as_float(u & 0xffff0000u) + __uint_as_float(u << 16);
        }
    }
    // tail GEMM: wave quadrant (mtj, nq).
    {
        int mtj = wv >> 1, nq = wv & 1;
        f32x4_t acc = {0.f, 0.f, 0.f, 0.f};
        for (int kk = 0; kk < 8; ++kk) {
            bf16x8_t Ehi = *reinterpret_cast<const bf16x8_t*>(
                tailA + ((kk * 2 + mtj) * 64 + lane) * 4);
            bf16x8_t Elo = *reinterpret_cast<const bf16x8_t*>(
                tailA + 4096 + ((kk * 2 + mtj) * 64 + lane) * 4);
            int base = (nq * 16 + l15) * 260 + kk * 32 + 8 * l4;
            uint4 va = *reinterpret_cast<const uint4*>(&sVvT[base]);
            uint4 vb = *reinterpret_cast<const uint4*>(&sVvT[base + 4]);
            bf16x8_t Vhi, Vlo;
            Vhi[0] = (short)(va.x >> 16); Vlo[0] = (short)(va.x & 0xffffu);
            Vhi[1] = (short)(va.y >> 16); Vlo[1] = (short)(va.y & 0xffffu);
            Vhi[2] = (short)(va.z >> 16); Vlo[2] = (short)(va.z & 0xffffu);
            Vhi[3] = (short)(va.w >> 16); Vlo[3] = (short)(va.w & 0xffffu);
            Vhi[4] = (short)(vb.x >> 16); Vlo[4] = (short)(vb.x & 0xffffu);
            Vhi[5] = (short)(vb.y >> 16); Vlo[5] = (short)(vb.y & 0xffffu);
            Vhi[6] = (short)(vb.z >> 16); Vlo[6] = (short)(vb.z & 0xffffu);
            Vhi[7] = (short)(vb.w >> 16); Vlo[7] = (short)(vb.w & 0xffffu);
            acc = __builtin_amdgcn_mfma_f32_16x16x32_bf16(Ehi, Vhi, acc, 0, 0, 0);
            acc = __builtin_amdgcn_mfma_f32_16x16x32_bf16(Ehi, Vlo, acc, 0, 0, 0);
            acc = __builtin_amdgcn_mfma_f32_16x16x32_bf16(Elo, Vhi, acc, 0, 0, 0);
        }
        int j0 = mtj * 16 + l4 * 4;
        if (j0 < 24) {
            float4 st = {acc[0], acc[1], acc[2], acc[3]};
            *reinterpret_cast<float4*>(
                tmp + (size_t)(b * 32 + nq * 16 + l15) * 6144 + x * 24 + j0) = st;
        }
    }
}

// Layer 3 (no gelu) + final MLP (R11 MFMA phase B) from packed sVvT.
__global__ __launch_bounds__(256) void k_dinvmlp(const float* __restrict__ h,
                                                 const float* __restrict__ g,
                                                 const unsigned* __restrict__ specA,
                                                 const unsigned* __restrict__ cwB,
                                                 const float* __restrict__ cb,
                                                 const unsigned* __restrict__ wB,
                                                 const float* __restrict__ b0,
                                                 const float* __restrict__ w1p,
                                                 const float* __restrict__ b1,
                                                 float* __restrict__ out) {
    __shared__ unsigned sVvT[32 * 260];
    __shared__ float sOut[256 * 5];
    int b = blockIdx.x >> 8, x = blockIdx.x & 255;
    int tid = threadIdx.x, wv = tid >> 6, lane = tid & 63;
    int l15 = lane & 15, l4 = lane >> 4;
    dinv_phaseA<0>(h, g, specA, cwB, cb, sVvT, b, x, 3, wv, lane);
    __syncthreads();
    // Phase B: T = V @ W0, gelu, contract with W1 (R11-verified layout).
    bf16x8_t Ahi[4], Alo[4];
#pragma unroll
    for (int mt = 0; mt < 4; ++mt) {
        int rowY = (wv << 6) + (mt << 4) + l15;
#pragma unroll
        for (int j = 0; j < 8; ++j) {
            unsigned u = sVvT[(8 * l4 + j) * 260 + rowY];
            Ahi[mt][j] = (short)(u >> 16);
            Alo[mt][j] = (short)(u & 0xffffu);
        }
    }
    float apart[4][4][3];
#pragma unroll
    for (int mt = 0; mt < 4; ++mt)
#pragma unroll
        for (int r = 0; r < 4; ++r)
#pragma unroll
            for (int c = 0; c < 3; ++c) apart[mt][r][c] = 0.f;
    for (int n = 0; n < 8; ++n) {
        bf16x8_t Bhi = *reinterpret_cast<const bf16x8_t*>(wB + (n * 64 + lane) * 4);
        bf16x8_t Blo = *reinterpret_cast<const bf16x8_t*>(wB + 2048 + (n * 64 + lane) * 4);
        int km = (n << 4) + l15;
        float b0v  = b0[km];
        float w1v0 = w1p[km], w1v1 = w1p[128 + km], w1v2 = w1p[256 + km];
#pragma unroll
        for (int mt = 0; mt < 4; ++mt) {
            f32x4_t acc = {0.f, 0.f, 0.f, 0.f};
            acc = __builtin_amdgcn_mfma_f32_16x16x32_bf16(Ahi[mt], Bhi, acc, 0, 0, 0);
            acc = __builtin_amdgcn_mfma_f32_16x16x32_bf16(Ahi[mt], Blo, acc, 0, 0, 0);
            acc = __builtin_amdgcn_mfma_f32_16x16x32_bf16(Alo[mt], Bhi, acc, 0, 0, 0);
#pragma unroll
            for (int r = 0; r < 4; ++r) {
                float tg = fgelu(acc[r] + b0v);
                apart[mt][r][0] = __builtin_fmaf(tg, w1v0, apart[mt][r][0]);
                apart[mt][r][1] = __builtin_fmaf(tg, w1v1, apart[mt][r][1]);
                apart[mt][r][2] = __builtin_fmaf(tg, w1v2, apart[mt][r][2]);
            }
        }
    }
#pragma unroll
    for (int mt = 0; mt < 4; ++mt)
#pragma unroll
        for (int r = 0; r < 4; ++r)
#pragma unroll
            for (int c = 0; c < 3; ++c) {
                float v = apart[mt][r][c];
                v += __shfl_xor(v, 1);
                v += __shfl_xor(v, 2);
                v += __shfl_xor(v, 4);
                v += __shfl_xor(v, 8);
                if (l15 == 0)
                    sOut[((wv << 6) + (mt << 4) + (l4 << 2) + r) * 5 + c] = v;
            }
    __syncthreads();
    float b1v0 = b1[0], b1v1 = b1[1], b1v2 = b1[2];
    out[(((size_t)b * 3 + 0) * 256 + x) * 256 + tid] = sOut[tid * 5 + 0] + b1v0;
    out[(((size_t)b * 3 + 1) * 256 + x) * 256 + tid] = sOut[tid * 5 + 1] + b1v1;
    out[(((size_t)b * 3 + 2) * 256 + x) * 256 + tid] = sOut[tid * 5 + 2] + b1v2;
}

extern "C" void kernel_launch(void* const* d_in, const int* in_sizes, int n_in,
                              void* d_out, int out_size, void* d_ws, size_t ws_size,
                              hipStream_t stream) {
    const float* xin  = (const float*)d_in[0];
    const float* pw   = (const float*)d_in[1];
    const float* pb   = (const float*)d_in[2];
    const float* sw1r = (const float*)d_in[3];
    const float* sw1i = (const float*)d_in[4];
    const float* sw2r = (const float*)d_in[5];
    const float* sw2i = (const float*)d_in[6];
    const float* cw   = (const float*)d_in[7];
    const float* cb   = (const float*)d_in[8];
    const float* w0   = (const float*)d_in[9];
    const float* b0   = (const float*)d_in[10];
    const float* w1   = (const float*)d_in[11];
    const float* b1   = (const float*)d_in[12];
    float* out = (float*)d_out;

    unsigned* specA = (unsigned*)d_ws;         // 8192 u32
    unsigned* tailA = specA + 8192;            // 8192
    unsigned* cwB   = tailA + 8192;            // 4096
    unsigned* wB    = cwB + 4096;              // 4096
    float* w1p = (float*)(wB + 4096);          // 384
    float* h   = w1p + 384;                    // 8388608
    float* tmp = h + 8388608;                  // 786432 (aliased with g)
    float* hfp = tmp + 786432;                 // 294912
    float* g   = tmp;                          // alias

    k_init<<<1, 256, 0, stream>>>(w0, b0, w1, cw, specA, tailA, cwB, wB, w1p);
    k_liftf<<<1024, 256, 0, stream>>>(xin, pw, pb, h, tmp);
    for (int l = 0; l < 4; ++l) {
        k_dftx<<<512, 320, 0, stream>>>(tmp, hfp);
        k_mixcinv<<<128, 320, 0, stream>>>(hfp, sw1r, sw1i, sw2r, sw2i, g, l);
        if (l < 3)
            k_dinvf<<<1024, 256, 0, stream>>>(h, g, specA, tailA, cwB, cb, tmp, l);
        else
            k_dinvmlp<<<1024, 256, 0, stream>>>(h, g, specA, cwB, cb, wB, b0, w1p,
                                                b1, out);
    }
}